// Round 3
// baseline (669.275 us; speedup 1.0000x reference)
//
#include <hip/hip_runtime.h>
#include <cmath>

typedef unsigned int uint32;
typedef __bf16 bf16;
typedef __bf16 bf16x8 __attribute__((ext_vector_type(8)));
typedef float f32x4 __attribute__((ext_vector_type(4)));

#define LVLS 10
#define TSIZE 65536
#define TMASK 65535u
#define PRIME2 2654435761u
#define PRIME3 805459861u

// ---- ws layout (bytes) ----
//   [0,      18432): W1t/W2t/W3t bf16 images (9216 elems)
//   [18432,  18472): dq[10] f32  (scale/127 per level)
//   [18496,  18536): scales[10] u32 (absmax bits, atomicMax target; memset 0)
//   [18560, +2.6MB): biased-uint8 table [10][65536][4]  (value+128)
#define WOFF_W1 0
#define WOFF_W2 4096
#define WOFF_W3 8192
#define W_ELEMS 9216
#define DQ_OFF 18432
#define SC_OFF 18496
#define TAB_OFF_B 18560
#define TAB_ELEMS_F (LVLS * TSIZE * 4)
#define WS_NEEDED ((size_t)TAB_OFF_B + (size_t)TAB_ELEMS_F)

struct KParams { float resf[LVLS]; };

// ---------------- prep 1: per-level absmax ----------------
__global__ void scale_kernel(const float* __restrict__ tables, unsigned* __restrict__ scales) {
  int tid = blockIdx.x * 256 + threadIdx.x;
  int i4 = tid * 4;
  if (i4 >= TAB_ELEMS_F) return;
  float4 v = *(const float4*)(tables + i4);
  float m = fmaxf(fmaxf(fabsf(v.x), fabsf(v.y)), fmaxf(fabsf(v.z), fabsf(v.w)));
#pragma unroll
  for (int off = 32; off; off >>= 1) m = fmaxf(m, __shfl_xor(m, off, 64));
  if ((threadIdx.x & 63) == 0) {
    int l = i4 >> 18;
    atomicMax(scales + l, __float_as_uint(m));
  }
}

// ---------------- prep 2: weight transpose + biased-int8 quantize ----------------
__global__ void quant_kernel(const float* __restrict__ W1, const float* __restrict__ W2,
                             const float* __restrict__ W3, const float* __restrict__ tables,
                             char* __restrict__ ws8, int do_tab) {
  int tid = blockIdx.x * 256 + threadIdx.x;
  bf16* wsb = (bf16*)ws8;
  if (tid < W_ELEMS) {
    float v;
    if (tid < 4096) {
      int n = tid >> 6, k = tid & 63;
      v = (k < 40) ? W1[k * 64 + n] : 0.f;
    } else if (tid < 8192) {
      int t2 = tid - 4096; int n = t2 >> 6, k = t2 & 63;
      v = W2[k * 64 + n];
    } else {
      int t3 = tid - 8192; int n = t3 >> 6, k = t3 & 63;
      v = (n < 13) ? W3[k * 13 + n] : 0.f;
    }
    wsb[tid] = (bf16)v;
  }
  const unsigned* scales = (const unsigned*)(ws8 + SC_OFF);
  if (tid < LVLS) {
    float s = __uint_as_float(scales[tid]);
    ((float*)(ws8 + DQ_OFF))[tid] = s * (1.0f / 127.0f);
  }
  if (do_tab) {
    int i4 = tid * 4;
    if (i4 < TAB_ELEMS_F) {
      float4 v = *(const float4*)(tables + i4);
      int l = i4 >> 18;
      float s = __uint_as_float(scales[l]);
      float r = (s > 0.f) ? 127.f / s : 0.f;
      // biased: u = q + 128 in [1,255]; dequant via (Σw·u - 128)·dq (Σw == 1)
      int q0 = (int)rintf(fminf(fmaxf(v.x * r, -127.f), 127.f)) + 128;
      int q1 = (int)rintf(fminf(fmaxf(v.y * r, -127.f), 127.f)) + 128;
      int q2 = (int)rintf(fminf(fmaxf(v.z * r, -127.f), 127.f)) + 128;
      int q3 = (int)rintf(fminf(fmaxf(v.w * r, -127.f), 127.f)) + 128;
      unsigned p = (q0 & 0xff) | ((q1 & 0xff) << 8) | ((q2 & 0xff) << 16) | ((q3 & 0xff) << 24);
      *(unsigned*)(ws8 + TAB_OFF_B + i4) = p;
    }
  }
}

// ---------------- device helpers ----------------
__device__ __forceinline__ float ub0(uint32 q) {
#if __has_builtin(__builtin_amdgcn_cvt_f32_ubyte0)
  return __builtin_amdgcn_cvt_f32_ubyte0(q);
#else
  return (float)(q & 0xffu);
#endif
}
__device__ __forceinline__ float ub1(uint32 q) {
#if __has_builtin(__builtin_amdgcn_cvt_f32_ubyte1)
  return __builtin_amdgcn_cvt_f32_ubyte1(q);
#else
  return (float)((q >> 8) & 0xffu);
#endif
}
__device__ __forceinline__ float ub2(uint32 q) {
#if __has_builtin(__builtin_amdgcn_cvt_f32_ubyte2)
  return __builtin_amdgcn_cvt_f32_ubyte2(q);
#else
  return (float)((q >> 16) & 0xffu);
#endif
}
__device__ __forceinline__ float ub3(uint32 q) {
#if __has_builtin(__builtin_amdgcn_cvt_f32_ubyte3)
  return __builtin_amdgcn_cvt_f32_ubyte3(q);
#else
  return (float)(q >> 24);
#endif
}

__device__ __forceinline__ float rcp_fast(float v) {
#if __has_builtin(__builtin_amdgcn_rcpf)
  return __builtin_amdgcn_rcpf(v);
#else
  return 1.0f / v;
#endif
}

// Abramowitz-Stegun 7.1.26: |err| <= 1.5e-7 absolute for x >= 0.
__device__ __forceinline__ float erf_fast(float xv) {
  float t = rcp_fast(fmaf(0.3275911f, xv, 1.0f));
  float p = fmaf(fmaf(fmaf(fmaf(1.061405429f, t, -1.453152027f),
                           t, 1.421413741f), t, -0.284496736f), t, 0.254829592f);
  p *= t;
  float e = __expf(-xv * xv);   // x=1e6 -> exp(-1e12)=0 -> erf=1
  return fmaf(-p, e, 1.0f);
}

__device__ __forceinline__ float selu_f(float v) {
  float neg = 1.6732632423543772f * (__expf(v) - 1.0f);
  return 1.0507009873554805f * (v > 0.f ? v : neg);
}

__device__ __forceinline__ void level_idx(float px, float py, float pz, float rs,
                                          uint32* idx, float& fx, float& fy, float& fz) {
  float xs = px * rs, ys = py * rs, zs = pz * rs;
  float bx = floorf(xs), by = floorf(ys), bz = floorf(zs);
  fx = xs - bx; fy = ys - by; fz = zs - bz;
  uint32 cx = (uint32)bx, cy = (uint32)by, cz = (uint32)bz;
  uint32 hx0 = cx, hx1 = cx + 1u;
  uint32 hy0 = cy * PRIME2, hy1 = hy0 + PRIME2;
  uint32 hz0 = cz * PRIME3, hz1 = hz0 + PRIME3;
  idx[0] = (hx0 ^ hy0 ^ hz0) & TMASK; idx[1] = (hx0 ^ hy0 ^ hz1) & TMASK;
  idx[2] = (hx0 ^ hy1 ^ hz0) & TMASK; idx[3] = (hx0 ^ hy1 ^ hz1) & TMASK;
  idx[4] = (hx1 ^ hy0 ^ hz0) & TMASK; idx[5] = (hx1 ^ hy0 ^ hz1) & TMASK;
  idx[6] = (hx1 ^ hy1 ^ hz0) & TMASK; idx[7] = (hx1 ^ hy1 ^ hz1) & TMASK;
}

__device__ __forceinline__ void gemm_stage(const bf16* __restrict__ Arow,
                                           const bf16* __restrict__ Bbase,
                                           const float* __restrict__ bvec,
                                           bf16* __restrict__ Hwr, int lr) {
  float bias[4];
#pragma unroll
  for (int nt = 0; nt < 4; ++nt) bias[nt] = bvec[nt * 16 + lr];
  f32x4 acc[4][4];
#pragma unroll
  for (int ms = 0; ms < 4; ++ms)
#pragma unroll
    for (int nt = 0; nt < 4; ++nt) {
      f32x4 a = {bias[nt], bias[nt], bias[nt], bias[nt]};
      acc[ms][nt] = a;
    }
  bf16x8 Bf[2][4];
#pragma unroll
  for (int ks = 0; ks < 2; ++ks)
#pragma unroll
    for (int nt = 0; nt < 4; ++nt)
      Bf[ks][nt] = *(const bf16x8*)(Bbase + nt * 1024 + ks * 32);
#pragma unroll
  for (int ks = 0; ks < 2; ++ks) {
    bf16x8 Af[4];
#pragma unroll
    for (int ms = 0; ms < 4; ++ms) Af[ms] = *(const bf16x8*)(Arow + ms * 1152 + ks * 32);
#pragma unroll
    for (int ms = 0; ms < 4; ++ms)
#pragma unroll
      for (int nt = 0; nt < 4; ++nt)
        acc[ms][nt] = __builtin_amdgcn_mfma_f32_16x16x32_bf16(Af[ms], Bf[ks][nt], acc[ms][nt], 0, 0, 0);
  }
#pragma unroll
  for (int ms = 0; ms < 4; ++ms)
#pragma unroll
    for (int nt = 0; nt < 4; ++nt)
#pragma unroll
      for (int r = 0; r < 4; ++r)
        Hwr[(ms * 16 + r) * 72 + nt * 16 + lr] = (bf16)selu_f(acc[ms][nt][r]);
}

// ---------------- fused encode + MLP ----------------
// 256 threads (4 waves), 256 points per block. Hbuf stride 72 (144B rows).
// Encode loop is software-pipelined one level ahead to hide L2 gather latency.
template <bool TB>
__global__ __launch_bounds__(256, 4)
void ngp_fused(const float* __restrict__ x, const float* __restrict__ cr,
               const float* __restrict__ tables, const char* __restrict__ ws8,
               const float* __restrict__ b1, const float* __restrict__ b2,
               const float* __restrict__ b3, float* __restrict__ out,
               int N, KParams kp) {
  __shared__ __align__(16) bf16 Hbuf[256 * 72];
  const int tid = threadIdx.x;
  const int n = blockIdx.x * 256 + tid;
  const int ncl = (n < N) ? n : 0;

  const float px = x[ncl * 3 + 0];
  const float py = x[ncl * 3 + 1];
  const float pz = x[ncl * 3 + 2];
  const float crv = cr[ncl];
  const float* dq = (const float*)(ws8 + DQ_OFF);

  float feat[40];
  if (TB) {
    const uint32* tb8 = (const uint32*)(ws8 + TAB_OFF_B);
    uint32 qA[8];
    float fxA, fyA, fzA;
    {
      uint32 idxA[8];
      level_idx(px, py, pz, kp.resf[0], idxA, fxA, fyA, fzA);
#pragma unroll
      for (int c = 0; c < 8; ++c) qA[c] = tb8[idxA[c]];
    }
#pragma unroll
    for (int l = 0; l < LVLS; ++l) {
      uint32 qB[8];
      float fxB, fyB, fzB;
      if (l < LVLS - 1) {
        uint32 idxB[8];
        level_idx(px, py, pz, kp.resf[l + 1], idxB, fxB, fyB, fzB);
        const uint32* base = tb8 + (l + 1) * TSIZE;
#pragma unroll
        for (int c = 0; c < 8; ++c) qB[c] = base[idxB[c]];
      }
      // consume level l
      float wx1 = fxA, wx0 = 1.f - fxA, wy1 = fyA, wy0 = 1.f - fyA, wz1 = fzA, wz0 = 1.f - fzA;
      float wxy00 = wx0 * wy0, wxy01 = wx0 * wy1, wxy10 = wx1 * wy0, wxy11 = wx1 * wy1;
      float w[8] = {wxy00 * wz0, wxy00 * wz1, wxy01 * wz0, wxy01 * wz1,
                    wxy10 * wz0, wxy10 * wz1, wxy11 * wz0, wxy11 * wz1};
      float a0 = 0.f, a1 = 0.f, a2 = 0.f, a3 = 0.f;
#pragma unroll
      for (int c = 0; c < 8; ++c) {
        a0 = fmaf(w[c], ub0(qA[c]), a0);
        a1 = fmaf(w[c], ub1(qA[c]), a1);
        a2 = fmaf(w[c], ub2(qA[c]), a2);
        a3 = fmaf(w[c], ub3(qA[c]), a3);
      }
      float s = erf_fast(rsqrtf(fmaxf(4.0f * (float)l * crv, 1e-12f))) * dq[l];
      float off = -128.f * s;
      feat[0 * 10 + l] = fmaf(a0, s, off);
      feat[1 * 10 + l] = fmaf(a1, s, off);
      feat[2 * 10 + l] = fmaf(a2, s, off);
      feat[3 * 10 + l] = fmaf(a3, s, off);
      if (l < LVLS - 1) {
#pragma unroll
        for (int c = 0; c < 8; ++c) qA[c] = qB[c];
        fxA = fxB; fyA = fyB; fzA = fzB;
      }
    }
  } else {
#pragma unroll
    for (int l = 0; l < LVLS; ++l) {
      uint32 idx[8];
      float fx, fy, fz;
      level_idx(px, py, pz, kp.resf[l], idx, fx, fy, fz);
      const float4* tb = ((const float4*)tables) + l * TSIZE;
      float f[8][4];
#pragma unroll
      for (int c = 0; c < 8; ++c) {
        float4 q = tb[idx[c]];
        f[c][0] = q.x; f[c][1] = q.y; f[c][2] = q.z; f[c][3] = q.w;
      }
      float wx1 = fx, wx0 = 1.f - fx, wy1 = fy, wy0 = 1.f - fy, wz1 = fz, wz0 = 1.f - fz;
      float wxy00 = wx0 * wy0, wxy01 = wx0 * wy1, wxy10 = wx1 * wy0, wxy11 = wx1 * wy1;
      float w[8] = {wxy00 * wz0, wxy00 * wz1, wxy01 * wz0, wxy01 * wz1,
                    wxy10 * wz0, wxy10 * wz1, wxy11 * wz0, wxy11 * wz1};
      float a0 = 0.f, a1 = 0.f, a2 = 0.f, a3 = 0.f;
#pragma unroll
      for (int c = 0; c < 8; ++c) {
        a0 = fmaf(w[c], f[c][0], a0);
        a1 = fmaf(w[c], f[c][1], a1);
        a2 = fmaf(w[c], f[c][2], a2);
        a3 = fmaf(w[c], f[c][3], a3);
      }
      float s = erf_fast(rsqrtf(fmaxf(4.0f * (float)l * crv, 1e-12f)));
      feat[0 * 10 + l] = a0 * s;
      feat[1 * 10 + l] = a1 * s;
      feat[2 * 10 + l] = a2 * s;
      feat[3 * 10 + l] = a3 * s;
    }
  }

  {
    bf16* row = Hbuf + tid * 72;
#pragma unroll
    for (int c = 0; c < 5; ++c) {
      bf16x8 v;
#pragma unroll
      for (int j = 0; j < 8; ++j) v[j] = (bf16)feat[c * 8 + j];
      *(bf16x8*)(row + c * 8) = v;
    }
    bf16x8 z;
#pragma unroll
    for (int j = 0; j < 8; ++j) z[j] = (bf16)0.f;
    *(bf16x8*)(row + 40) = z;
    *(bf16x8*)(row + 48) = z;
    *(bf16x8*)(row + 56) = z;
  }
  __syncthreads();

  const int w = tid >> 6;
  const int lane = tid & 63;
  const int lr = lane & 15;
  const int quad = lane >> 4;
  const bf16* wsb = (const bf16*)ws8;

  const bf16* Arow = Hbuf + (w * 64 + lr) * 72 + quad * 8;
  bf16* Hwr = Hbuf + (w * 64 + quad * 4) * 72;

  gemm_stage(Arow, wsb + WOFF_W1 + lr * 64 + quad * 8, b1, Hwr, lr);
  __syncthreads();
  gemm_stage(Arow, wsb + WOFF_W2 + lr * 64 + quad * 8, b2, Hwr, lr);
  __syncthreads();

  // GEMM3: [64x64] @ [64x13pad16], then coalesced store via LDS staging.
  f32x4 acc3[4];
  {
    float b3v = (lr < 13) ? b3[lr] : 0.f;
#pragma unroll
    for (int ms = 0; ms < 4; ++ms) {
      f32x4 a = {b3v, b3v, b3v, b3v};
      acc3[ms] = a;
    }
    const bf16* B3b = wsb + WOFF_W3 + lr * 64 + quad * 8;
    bf16x8 B3[2];
    B3[0] = *(const bf16x8*)(B3b);
    B3[1] = *(const bf16x8*)(B3b + 32);
#pragma unroll
    for (int ks = 0; ks < 2; ++ks) {
      bf16x8 Af[4];
#pragma unroll
      for (int ms = 0; ms < 4; ++ms) Af[ms] = *(const bf16x8*)(Arow + ms * 1152 + ks * 32);
#pragma unroll
      for (int ms = 0; ms < 4; ++ms)
        acc3[ms] = __builtin_amdgcn_mfma_f32_16x16x32_bf16(Af[ms], B3[ks], acc3[ms], 0, 0, 0);
    }
  }
  __syncthreads();  // all A-frag reads done; Hbuf reused as f32 out staging
  float* ob = (float*)Hbuf;  // 256*13 = 3328 floats (13312 B < 36 KB)
  if (lr < 13) {
#pragma unroll
    for (int ms = 0; ms < 4; ++ms)
#pragma unroll
      for (int r = 0; r < 4; ++r)
        ob[(w * 64 + quad * 4 + ms * 16 + r) * 13 + lr] = acc3[ms][r];
  }
  __syncthreads();
  const int base = blockIdx.x * (256 * 13);
  if ((blockIdx.x + 1) * 256 <= N) {
    const float4* obv = (const float4*)ob;
    float4* og = (float4*)(out + base);
#pragma unroll
    for (int i = tid; i < 832; i += 256) og[i] = obv[i];
  } else {
    const int lim = N * 13 - base;
    for (int i = tid; i < 256 * 13; i += 256)
      if (i < lim) out[base + i] = ob[i];
  }
}

// ---------------- host ----------------
extern "C" void kernel_launch(void* const* d_in, const int* in_sizes, int n_in,
                              void* d_out, int out_size, void* d_ws, size_t ws_size,
                              hipStream_t stream) {
  const float* x      = (const float*)d_in[0];
  const float* cr     = (const float*)d_in[1];
  const float* tables = (const float*)d_in[2];
  const float* W1     = (const float*)d_in[3];
  const float* b1     = (const float*)d_in[4];
  const float* W2     = (const float*)d_in[5];
  const float* b2     = (const float*)d_in[6];
  const float* W3     = (const float*)d_in[7];
  const float* b3     = (const float*)d_in[8];
  float* out = (float*)d_out;
  const int N = in_sizes[1];

  // RES with the exact double arithmetic Python uses (bit-identical hashing).
  KParams kp;
  double B = exp((log(16.0 * pow(2.0, 10.0)) - log(16.0)) / 9.0);
  for (int l = 0; l < LVLS; ++l) kp.resf[l] = (float)floor(16.0 * pow(B, (double)l));

  char* ws8 = (char*)d_ws;
  const bool tb = ws_size >= WS_NEEDED;

  const int qblocks = (TAB_ELEMS_F / 4 + 255) / 256;
  if (tb) {
    hipMemsetAsync(ws8 + SC_OFF, 0, 64, stream);
    scale_kernel<<<qblocks, 256, 0, stream>>>(tables, (unsigned*)(ws8 + SC_OFF));
    quant_kernel<<<qblocks, 256, 0, stream>>>(W1, W2, W3, tables, ws8, 1);
  } else {
    quant_kernel<<<(W_ELEMS + 255) / 256, 256, 0, stream>>>(W1, W2, W3, tables, ws8, 0);
  }

  int blocks = (N + 255) / 256;
  if (tb)
    ngp_fused<true><<<blocks, 256, 0, stream>>>(x, cr, tables, ws8, b1, b2, b3, out, N, kp);
  else
    ngp_fused<false><<<blocks, 256, 0, stream>>>(x, cr, tables, ws8, b1, b2, b3, out, N, kp);
}

// Round 6
// 563.845 us; speedup vs baseline: 1.1870x; 1.1870x over previous
//
#include <hip/hip_runtime.h>
#include <cmath>

typedef unsigned int uint32;
typedef __bf16 bf16;
typedef __bf16 bf16x4 __attribute__((ext_vector_type(4)));
typedef __bf16 bf16x8 __attribute__((ext_vector_type(8)));
typedef float f32x4 __attribute__((ext_vector_type(4)));

#define LVLS 10
#define TSIZE 65536
#define TMASK 65535u
#define PRIME2 2654435761u
#define PRIME3 805459861u

// ---- ws layout (bytes) ----
//   [0,      18432): W1t/W2t/W3t bf16 images (9216 elems), UNPERMUTED k order
//   [18432,  18472): dq[10] f32  (scale/127 per level)
//   [18496,  18536): scales[10] u32 (absmax bits, atomicMax target; memset 0)
//   [18560, +2.6MB): biased-uint8 table [10][65536][4]  (value+128)
#define WOFF_W1 0
#define WOFF_W2 4096
#define WOFF_W3 8192
#define W_ELEMS 9216
#define DQ_OFF 18432
#define SC_OFF 18496
#define TAB_OFF_B 18560
#define TAB_ELEMS_F (LVLS * TSIZE * 4)
#define WS_NEEDED ((size_t)TAB_OFF_B + (size_t)TAB_ELEMS_F)

struct KParams { float resf[LVLS]; };

// ---------------- prep 1: per-level absmax ----------------
__global__ void scale_kernel(const float* __restrict__ tables, unsigned* __restrict__ scales) {
  int tid = blockIdx.x * 256 + threadIdx.x;
  int i4 = tid * 4;
  if (i4 >= TAB_ELEMS_F) return;
  float4 v = *(const float4*)(tables + i4);
  float m = fmaxf(fmaxf(fabsf(v.x), fabsf(v.y)), fmaxf(fabsf(v.z), fabsf(v.w)));
#pragma unroll
  for (int off = 32; off; off >>= 1) m = fmaxf(m, __shfl_xor(m, off, 64));
  if ((threadIdx.x & 63) == 0) {
    int l = i4 >> 18;
    atomicMax(scales + l, __float_as_uint(m));
  }
}

// ---------------- prep 2: weight transpose + biased-int8 quantize ----------------
__global__ void quant_kernel(const float* __restrict__ W1, const float* __restrict__ W2,
                             const float* __restrict__ W3, const float* __restrict__ tables,
                             char* __restrict__ ws8, int do_tab) {
  int tid = blockIdx.x * 256 + threadIdx.x;
  bf16* wsb = (bf16*)ws8;
  if (tid < W_ELEMS) {
    float v;
    if (tid < 4096) {
      int n = tid >> 6, k = tid & 63;
      v = (k < 40) ? W1[k * 64 + n] : 0.f;     // unpermuted (R2/R3-proven)
    } else if (tid < 8192) {
      int t2 = tid - 4096; int n = t2 >> 6, k = t2 & 63;
      v = W2[k * 64 + n];
    } else {
      int t3 = tid - 8192; int n = t3 >> 6, k = t3 & 63;
      v = (n < 13) ? W3[k * 13 + n] : 0.f;
    }
    wsb[tid] = (bf16)v;
  }
  const unsigned* scales = (const unsigned*)(ws8 + SC_OFF);
  if (tid < LVLS) {
    float s = __uint_as_float(scales[tid]);
    ((float*)(ws8 + DQ_OFF))[tid] = s * (1.0f / 127.0f);
  }
  if (do_tab) {
    int i4 = tid * 4;
    if (i4 < TAB_ELEMS_F) {
      float4 v = *(const float4*)(tables + i4);
      int l = i4 >> 18;
      float s = __uint_as_float(scales[l]);
      float r = (s > 0.f) ? 127.f / s : 0.f;
      int q0 = (int)rintf(fminf(fmaxf(v.x * r, -127.f), 127.f)) + 128;
      int q1 = (int)rintf(fminf(fmaxf(v.y * r, -127.f), 127.f)) + 128;
      int q2 = (int)rintf(fminf(fmaxf(v.z * r, -127.f), 127.f)) + 128;
      int q3 = (int)rintf(fminf(fmaxf(v.w * r, -127.f), 127.f)) + 128;
      unsigned p = (q0 & 0xff) | ((q1 & 0xff) << 8) | ((q2 & 0xff) << 16) | ((q3 & 0xff) << 24);
      *(unsigned*)(ws8 + TAB_OFF_B + i4) = p;
    }
  }
}

// ---------------- device helpers ----------------
// Guarded: these builtins are absent in this ROCm clang; the fallback C
// expressions pattern-match to v_cvt_f32_ubyteN / v_rcp_f32 in the backend.
__device__ __forceinline__ float ub0(uint32 q) {
#if __has_builtin(__builtin_amdgcn_cvt_f32_ubyte0)
  return __builtin_amdgcn_cvt_f32_ubyte0(q);
#else
  return (float)(q & 0xffu);
#endif
}
__device__ __forceinline__ float ub1(uint32 q) {
#if __has_builtin(__builtin_amdgcn_cvt_f32_ubyte1)
  return __builtin_amdgcn_cvt_f32_ubyte1(q);
#else
  return (float)((q >> 8) & 0xffu);
#endif
}
__device__ __forceinline__ float ub2(uint32 q) {
#if __has_builtin(__builtin_amdgcn_cvt_f32_ubyte2)
  return __builtin_amdgcn_cvt_f32_ubyte2(q);
#else
  return (float)((q >> 16) & 0xffu);
#endif
}
__device__ __forceinline__ float ub3(uint32 q) {
#if __has_builtin(__builtin_amdgcn_cvt_f32_ubyte3)
  return __builtin_amdgcn_cvt_f32_ubyte3(q);
#else
  return (float)(q >> 24);
#endif
}

__device__ __forceinline__ float rcp_fast(float v) {
#if __has_builtin(__builtin_amdgcn_rcpf)
  return __builtin_amdgcn_rcpf(v);
#else
  return 1.0f / v;
#endif
}

// Abramowitz-Stegun 7.1.26: |err| <= 1.5e-7 absolute for x >= 0.
__device__ __forceinline__ float erf_fast(float xv) {
  float t = rcp_fast(fmaf(0.3275911f, xv, 1.0f));
  float p = fmaf(fmaf(fmaf(fmaf(1.061405429f, t, -1.453152027f),
                           t, 1.421413741f), t, -0.284496736f), t, 0.254829592f);
  p *= t;
  float e = __expf(-xv * xv);
  return fmaf(-p, e, 1.0f);
}

__device__ __forceinline__ float selu_f(float v) {
  float neg = 1.6732632423543772f * (__expf(v) - 1.0f);
  return 1.0507009873554805f * (v > 0.f ? v : neg);
}

__device__ __forceinline__ void level_idx(float px, float py, float pz, float rs,
                                          uint32* idx, float& fx, float& fy, float& fz) {
  float xs = px * rs, ys = py * rs, zs = pz * rs;
  float bx = floorf(xs), by = floorf(ys), bz = floorf(zs);
  fx = xs - bx; fy = ys - by; fz = zs - bz;
  uint32 cx = (uint32)bx, cy = (uint32)by, cz = (uint32)bz;
  uint32 hx0 = cx, hx1 = cx + 1u;
  uint32 hy0 = cy * PRIME2, hy1 = hy0 + PRIME2;
  uint32 hz0 = cz * PRIME3, hz1 = hz0 + PRIME3;
  idx[0] = (hx0 ^ hy0 ^ hz0) & TMASK; idx[1] = (hx0 ^ hy0 ^ hz1) & TMASK;
  idx[2] = (hx0 ^ hy1 ^ hz0) & TMASK; idx[3] = (hx0 ^ hy1 ^ hz1) & TMASK;
  idx[4] = (hx1 ^ hy0 ^ hz0) & TMASK; idx[5] = (hx1 ^ hy0 ^ hz1) & TMASK;
  idx[6] = (hx1 ^ hy1 ^ hz0) & TMASK; idx[7] = (hx1 ^ hy1 ^ hz1) & TMASK;
}

__device__ __forceinline__ void gemm_stage(const bf16* __restrict__ Arow,
                                           const bf16* __restrict__ Bbase,
                                           const float* __restrict__ bvec,
                                           bf16* __restrict__ Hwr, int lr) {
  float bias[4];
#pragma unroll
  for (int nt = 0; nt < 4; ++nt) bias[nt] = bvec[nt * 16 + lr];
  f32x4 acc[4][4];
#pragma unroll
  for (int ms = 0; ms < 4; ++ms)
#pragma unroll
    for (int nt = 0; nt < 4; ++nt) {
      f32x4 a = {bias[nt], bias[nt], bias[nt], bias[nt]};
      acc[ms][nt] = a;
    }
  bf16x8 Bf[2][4];
#pragma unroll
  for (int ks = 0; ks < 2; ++ks)
#pragma unroll
    for (int nt = 0; nt < 4; ++nt)
      Bf[ks][nt] = *(const bf16x8*)(Bbase + nt * 1024 + ks * 32);
#pragma unroll
  for (int ks = 0; ks < 2; ++ks) {
    bf16x8 Af[4];
#pragma unroll
    for (int ms = 0; ms < 4; ++ms) Af[ms] = *(const bf16x8*)(Arow + ms * 1152 + ks * 32);
#pragma unroll
    for (int ms = 0; ms < 4; ++ms)
#pragma unroll
      for (int nt = 0; nt < 4; ++nt)
        acc[ms][nt] = __builtin_amdgcn_mfma_f32_16x16x32_bf16(Af[ms], Bf[ks][nt], acc[ms][nt], 0, 0, 0);
  }
#pragma unroll
  for (int ms = 0; ms < 4; ++ms)
#pragma unroll
    for (int nt = 0; nt < 4; ++nt)
#pragma unroll
      for (int r = 0; r < 4; ++r)
        Hwr[(ms * 16 + r) * 72 + nt * 16 + lr] = (bf16)selu_f(acc[ms][nt][r]);
}

// ---------------- fused encode + MLP ----------------
// 256 threads (4 waves), 256 points per block. Hbuf stride 72 (144B rows).
// __launch_bounds__(256) WITHOUT a min-waves arg: R3 showed that pinning the
// allocator at the 64-VGPR bucket forces scratch spills (+480MB HBM traffic);
// LDS (36KB) already caps us at 4 blocks/CU, so let VGPRs float to ~128.
template <bool TB>
__global__ __launch_bounds__(256)
void ngp_fused(const float* __restrict__ x, const float* __restrict__ cr,
               const float* __restrict__ tables, const char* __restrict__ ws8,
               const float* __restrict__ b1, const float* __restrict__ b2,
               const float* __restrict__ b3, float* __restrict__ out,
               int N, KParams kp) {
  __shared__ __align__(16) bf16 Hbuf[256 * 72];
  const int tid = threadIdx.x;
  const int n = blockIdx.x * 256 + tid;
  const int ncl = (n < N) ? n : 0;

  const float px = x[ncl * 3 + 0];
  const float py = x[ncl * 3 + 1];
  const float pz = x[ncl * 3 + 2];
  const float crv = cr[ncl];
  const float* dq = (const float*)(ws8 + DQ_OFF);

  float feat[40];
  if (TB) {
    const uint32* tb8 = (const uint32*)(ws8 + TAB_OFF_B);
    uint32 qA[8];
    float fxA, fyA, fzA;
    {
      uint32 idxA[8];
      level_idx(px, py, pz, kp.resf[0], idxA, fxA, fyA, fzA);
#pragma unroll
      for (int c = 0; c < 8; ++c) qA[c] = tb8[idxA[c]];
    }
#pragma unroll
    for (int l = 0; l < LVLS; ++l) {
      uint32 qB[8];
      float fxB, fyB, fzB;
      if (l < LVLS - 1) {
        uint32 idxB[8];
        level_idx(px, py, pz, kp.resf[l + 1], idxB, fxB, fyB, fzB);
        const uint32* base = tb8 + (l + 1) * TSIZE;
#pragma unroll
        for (int c = 0; c < 8; ++c) qB[c] = base[idxB[c]];
      }
      float wx1 = fxA, wx0 = 1.f - fxA, wy1 = fyA, wy0 = 1.f - fyA, wz1 = fzA, wz0 = 1.f - fzA;
      float wxy00 = wx0 * wy0, wxy01 = wx0 * wy1, wxy10 = wx1 * wy0, wxy11 = wx1 * wy1;
      float w[8] = {wxy00 * wz0, wxy00 * wz1, wxy01 * wz0, wxy01 * wz1,
                    wxy10 * wz0, wxy10 * wz1, wxy11 * wz0, wxy11 * wz1};
      float a0 = 0.f, a1 = 0.f, a2 = 0.f, a3 = 0.f;
#pragma unroll
      for (int c = 0; c < 8; ++c) {
        a0 = fmaf(w[c], ub0(qA[c]), a0);
        a1 = fmaf(w[c], ub1(qA[c]), a1);
        a2 = fmaf(w[c], ub2(qA[c]), a2);
        a3 = fmaf(w[c], ub3(qA[c]), a3);
      }
      float s = erf_fast(rsqrtf(fmaxf(4.0f * (float)l * crv, 1e-12f))) * dq[l];
      float off = -128.f * s;
      feat[0 * 10 + l] = fmaf(a0, s, off);
      feat[1 * 10 + l] = fmaf(a1, s, off);
      feat[2 * 10 + l] = fmaf(a2, s, off);
      feat[3 * 10 + l] = fmaf(a3, s, off);
      if (l < LVLS - 1) {
#pragma unroll
        for (int c = 0; c < 8; ++c) qA[c] = qB[c];
        fxA = fxB; fyA = fyB; fzA = fzB;
      }
    }
  } else {
#pragma unroll 1
    for (int l = 0; l < LVLS; ++l) {
      uint32 idx[8];
      float fx, fy, fz;
      level_idx(px, py, pz, kp.resf[l], idx, fx, fy, fz);
      const float4* tb = ((const float4*)tables) + l * TSIZE;
      float f[8][4];
#pragma unroll
      for (int c = 0; c < 8; ++c) {
        float4 q = tb[idx[c]];
        f[c][0] = q.x; f[c][1] = q.y; f[c][2] = q.z; f[c][3] = q.w;
      }
      float wx1 = fx, wx0 = 1.f - fx, wy1 = fy, wy0 = 1.f - fy, wz1 = fz, wz0 = 1.f - fz;
      float wxy00 = wx0 * wy0, wxy01 = wx0 * wy1, wxy10 = wx1 * wy0, wxy11 = wx1 * wy1;
      float w[8] = {wxy00 * wz0, wxy00 * wz1, wxy01 * wz0, wxy01 * wz1,
                    wxy10 * wz0, wxy10 * wz1, wxy11 * wz0, wxy11 * wz1};
      float a0 = 0.f, a1 = 0.f, a2 = 0.f, a3 = 0.f;
#pragma unroll
      for (int c = 0; c < 8; ++c) {
        a0 = fmaf(w[c], f[c][0], a0);
        a1 = fmaf(w[c], f[c][1], a1);
        a2 = fmaf(w[c], f[c][2], a2);
        a3 = fmaf(w[c], f[c][3], a3);
      }
      float s = erf_fast(rsqrtf(fmaxf(4.0f * (float)l * crv, 1e-12f)));
      feat[0 * 10 + l] = a0 * s;
      feat[1 * 10 + l] = a1 * s;
      feat[2 * 10 + l] = a2 * s;
      feat[3 * 10 + l] = a3 * s;
    }
  }

  {
    bf16* row = Hbuf + tid * 72;
#pragma unroll
    for (int c = 0; c < 5; ++c) {
      bf16x8 v;
#pragma unroll
      for (int j = 0; j < 8; ++j) v[j] = (bf16)feat[c * 8 + j];
      *(bf16x8*)(row + c * 8) = v;
    }
    bf16x8 z;
#pragma unroll
    for (int j = 0; j < 8; ++j) z[j] = (bf16)0.f;
    *(bf16x8*)(row + 40) = z;
    *(bf16x8*)(row + 48) = z;
    *(bf16x8*)(row + 56) = z;
  }
  __syncthreads();

  const int w = tid >> 6;
  const int lane = tid & 63;
  const int lr = lane & 15;
  const int quad = lane >> 4;
  const bf16* wsb = (const bf16*)ws8;

  const bf16* Arow = Hbuf + (w * 64 + lr) * 72 + quad * 8;
  bf16* Hwr = Hbuf + (w * 64 + quad * 4) * 72;

  gemm_stage(Arow, wsb + WOFF_W1 + lr * 64 + quad * 8, b1, Hwr, lr);
  __syncthreads();
  gemm_stage(Arow, wsb + WOFF_W2 + lr * 64 + quad * 8, b2, Hwr, lr);
  __syncthreads();

  // GEMM3: [64x64] @ [64x13pad16], then coalesced store via LDS staging.
  f32x4 acc3[4];
  {
    float b3v = (lr < 13) ? b3[lr] : 0.f;
#pragma unroll
    for (int ms = 0; ms < 4; ++ms) {
      f32x4 a = {b3v, b3v, b3v, b3v};
      acc3[ms] = a;
    }
    const bf16* B3b = wsb + WOFF_W3 + lr * 64 + quad * 8;
    bf16x8 B3[2];
    B3[0] = *(const bf16x8*)(B3b);
    B3[1] = *(const bf16x8*)(B3b + 32);
#pragma unroll
    for (int ks = 0; ks < 2; ++ks) {
      bf16x8 Af[4];
#pragma unroll
      for (int ms = 0; ms < 4; ++ms) Af[ms] = *(const bf16x8*)(Arow + ms * 1152 + ks * 32);
#pragma unroll
      for (int ms = 0; ms < 4; ++ms)
        acc3[ms] = __builtin_amdgcn_mfma_f32_16x16x32_bf16(Af[ms], B3[ks], acc3[ms], 0, 0, 0);
    }
  }
  __syncthreads();  // all A-frag reads done; Hbuf reused as f32 out staging
  float* ob = (float*)Hbuf;  // 256*13 floats = 13312 B < 36 KB
  if (lr < 13) {
#pragma unroll
    for (int ms = 0; ms < 4; ++ms)
#pragma unroll
      for (int r = 0; r < 4; ++r)
        ob[(w * 64 + quad * 4 + ms * 16 + r) * 13 + lr] = acc3[ms][r];
  }
  __syncthreads();
  const int base = blockIdx.x * (256 * 13);
  if ((blockIdx.x + 1) * 256 <= N) {
    const float4* obv = (const float4*)ob;
    float4* og = (float4*)(out + base);
#pragma unroll
    for (int i = tid; i < 832; i += 256) og[i] = obv[i];
  } else {
    const int lim = N * 13 - base;
    for (int i = tid; i < 256 * 13; i += 256)
      if (i < lim) out[base + i] = ob[i];
  }
}

// ---------------- host ----------------
extern "C" void kernel_launch(void* const* d_in, const int* in_sizes, int n_in,
                              void* d_out, int out_size, void* d_ws, size_t ws_size,
                              hipStream_t stream) {
  const float* x      = (const float*)d_in[0];
  const float* cr     = (const float*)d_in[1];
  const float* tables = (const float*)d_in[2];
  const float* W1     = (const float*)d_in[3];
  const float* b1     = (const float*)d_in[4];
  const float* W2     = (const float*)d_in[5];
  const float* b2     = (const float*)d_in[6];
  const float* W3     = (const float*)d_in[7];
  const float* b3     = (const float*)d_in[8];
  float* out = (float*)d_out;
  const int N = in_sizes[1];

  // RES with the exact double arithmetic Python uses (bit-identical hashing).
  KParams kp;
  double B = exp((log(16.0 * pow(2.0, 10.0)) - log(16.0)) / 9.0);
  for (int l = 0; l < LVLS; ++l) kp.resf[l] = (float)floor(16.0 * pow(B, (double)l));

  char* ws8 = (char*)d_ws;
  const bool tb = ws_size >= WS_NEEDED;

  const int qblocks = (TAB_ELEMS_F / 4 + 255) / 256;
  if (tb) {
    (void)hipMemsetAsync(ws8 + SC_OFF, 0, 64, stream);
    scale_kernel<<<qblocks, 256, 0, stream>>>(tables, (unsigned*)(ws8 + SC_OFF));
    quant_kernel<<<qblocks, 256, 0, stream>>>(W1, W2, W3, tables, ws8, 1);
  } else {
    quant_kernel<<<(W_ELEMS + 255) / 256, 256, 0, stream>>>(W1, W2, W3, tables, ws8, 0);
  }

  int blocks = (N + 255) / 256;
  if (tb)
    ngp_fused<true><<<blocks, 256, 0, stream>>>(x, cr, tables, ws8, b1, b2, b3, out, N, kp);
  else
    ngp_fused<false><<<blocks, 256, 0, stream>>>(x, cr, tables, ws8, b1, b2, b3, out, N, kp);
}

// Round 7
// 544.470 us; speedup vs baseline: 1.2292x; 1.0356x over previous
//
#include <hip/hip_runtime.h>
#include <cmath>

typedef unsigned int uint32;
typedef __bf16 bf16;
typedef __bf16 bf16x4 __attribute__((ext_vector_type(4)));
typedef __bf16 bf16x8 __attribute__((ext_vector_type(8)));
typedef float f32x4 __attribute__((ext_vector_type(4)));

#define LVLS 10
#define TSIZE 65536
#define TMASK 65535u
#define PRIME2 2654435761u
#define PRIME3 805459861u

// ---- ws layout (bytes) ----
//   [0,      18432): W1t/W2t/W3t bf16 images (9216 elems), UNPERMUTED k order
//   [18432,  18472): dq[10] f32  (scale/127 per level)
//   [18496,  18536): scales[10] u32 (absmax bits; memset 0)
//   [18560, 2640000): biased-uint8 table [10][65536][4]  (value+128)
//   [2640128, ...):  bf16 features, block-chunked SoA: [blk][c=0..4][256 thr][8 bf16]
#define WOFF_W1 0
#define WOFF_W2 4096
#define WOFF_W3 8192
#define W_ELEMS 9216
#define DQ_OFF 18432
#define SC_OFF 18496
#define TAB_OFF_B 18560
#define TAB_ELEMS_F (LVLS * TSIZE * 4)
#define WS_TAB_NEEDED ((size_t)TAB_OFF_B + (size_t)TAB_ELEMS_F)
#define FEAT_OFF 2640128
#define FEAT_BLK_BYTES 20480   // 5 chunks * 256 threads * 16 B

struct KParams { float resf[LVLS]; };

// ---------------- prep 1: per-level absmax ----------------
__global__ void scale_kernel(const float* __restrict__ tables, unsigned* __restrict__ scales) {
  int tid = blockIdx.x * 256 + threadIdx.x;
  int i4 = tid * 4;
  if (i4 >= TAB_ELEMS_F) return;
  float4 v = *(const float4*)(tables + i4);
  float m = fmaxf(fmaxf(fabsf(v.x), fabsf(v.y)), fmaxf(fabsf(v.z), fabsf(v.w)));
#pragma unroll
  for (int off = 32; off; off >>= 1) m = fmaxf(m, __shfl_xor(m, off, 64));
  if ((threadIdx.x & 63) == 0) {
    int l = i4 >> 18;
    atomicMax(scales + l, __float_as_uint(m));
  }
}

// ---------------- prep 2: weight transpose + biased-int8 quantize ----------------
__global__ void quant_kernel(const float* __restrict__ W1, const float* __restrict__ W2,
                             const float* __restrict__ W3, const float* __restrict__ tables,
                             char* __restrict__ ws8, int do_tab) {
  int tid = blockIdx.x * 256 + threadIdx.x;
  bf16* wsb = (bf16*)ws8;
  if (tid < W_ELEMS) {
    float v;
    if (tid < 4096) {
      int n = tid >> 6, k = tid & 63;
      v = (k < 40) ? W1[k * 64 + n] : 0.f;
    } else if (tid < 8192) {
      int t2 = tid - 4096; int n = t2 >> 6, k = t2 & 63;
      v = W2[k * 64 + n];
    } else {
      int t3 = tid - 8192; int n = t3 >> 6, k = t3 & 63;
      v = (n < 13) ? W3[k * 13 + n] : 0.f;
    }
    wsb[tid] = (bf16)v;
  }
  const unsigned* scales = (const unsigned*)(ws8 + SC_OFF);
  if (tid < LVLS) {
    float s = __uint_as_float(scales[tid]);
    ((float*)(ws8 + DQ_OFF))[tid] = s * (1.0f / 127.0f);
  }
  if (do_tab) {
    int i4 = tid * 4;
    if (i4 < TAB_ELEMS_F) {
      float4 v = *(const float4*)(tables + i4);
      int l = i4 >> 18;
      float s = __uint_as_float(scales[l]);
      float r = (s > 0.f) ? 127.f / s : 0.f;
      int q0 = (int)rintf(fminf(fmaxf(v.x * r, -127.f), 127.f)) + 128;
      int q1 = (int)rintf(fminf(fmaxf(v.y * r, -127.f), 127.f)) + 128;
      int q2 = (int)rintf(fminf(fmaxf(v.z * r, -127.f), 127.f)) + 128;
      int q3 = (int)rintf(fminf(fmaxf(v.w * r, -127.f), 127.f)) + 128;
      unsigned p = (q0 & 0xff) | ((q1 & 0xff) << 8) | ((q2 & 0xff) << 16) | ((q3 & 0xff) << 24);
      *(unsigned*)(ws8 + TAB_OFF_B + i4) = p;
    }
  }
}

// ---------------- device helpers ----------------
__device__ __forceinline__ float ub0(uint32 q) {
#if __has_builtin(__builtin_amdgcn_cvt_f32_ubyte0)
  return __builtin_amdgcn_cvt_f32_ubyte0(q);
#else
  return (float)(q & 0xffu);
#endif
}
__device__ __forceinline__ float ub1(uint32 q) {
#if __has_builtin(__builtin_amdgcn_cvt_f32_ubyte1)
  return __builtin_amdgcn_cvt_f32_ubyte1(q);
#else
  return (float)((q >> 8) & 0xffu);
#endif
}
__device__ __forceinline__ float ub2(uint32 q) {
#if __has_builtin(__builtin_amdgcn_cvt_f32_ubyte2)
  return __builtin_amdgcn_cvt_f32_ubyte2(q);
#else
  return (float)((q >> 16) & 0xffu);
#endif
}
__device__ __forceinline__ float ub3(uint32 q) {
#if __has_builtin(__builtin_amdgcn_cvt_f32_ubyte3)
  return __builtin_amdgcn_cvt_f32_ubyte3(q);
#else
  return (float)(q >> 24);
#endif
}

__device__ __forceinline__ float rcp_fast(float v) {
#if __has_builtin(__builtin_amdgcn_rcpf)
  return __builtin_amdgcn_rcpf(v);
#else
  return 1.0f / v;
#endif
}

// Abramowitz-Stegun 7.1.26: |err| <= 1.5e-7 absolute for x >= 0.
__device__ __forceinline__ float erf_fast(float xv) {
  float t = rcp_fast(fmaf(0.3275911f, xv, 1.0f));
  float p = fmaf(fmaf(fmaf(fmaf(1.061405429f, t, -1.453152027f),
                           t, 1.421413741f), t, -0.284496736f), t, 0.254829592f);
  p *= t;
  float e = __expf(-xv * xv);
  return fmaf(-p, e, 1.0f);
}

__device__ __forceinline__ float selu_f(float v) {
  float neg = 1.6732632423543772f * (__expf(v) - 1.0f);
  return 1.0507009873554805f * (v > 0.f ? v : neg);
}

__device__ __forceinline__ void level_idx(float px, float py, float pz, float rs,
                                          uint32* idx, float& fx, float& fy, float& fz) {
  float xs = px * rs, ys = py * rs, zs = pz * rs;
  float bx = floorf(xs), by = floorf(ys), bz = floorf(zs);
  fx = xs - bx; fy = ys - by; fz = zs - bz;
  uint32 cx = (uint32)bx, cy = (uint32)by, cz = (uint32)bz;
  uint32 hx0 = cx, hx1 = cx + 1u;
  uint32 hy0 = cy * PRIME2, hy1 = hy0 + PRIME2;
  uint32 hz0 = cz * PRIME3, hz1 = hz0 + PRIME3;
  idx[0] = (hx0 ^ hy0 ^ hz0) & TMASK; idx[1] = (hx0 ^ hy0 ^ hz1) & TMASK;
  idx[2] = (hx0 ^ hy1 ^ hz0) & TMASK; idx[3] = (hx0 ^ hy1 ^ hz1) & TMASK;
  idx[4] = (hx1 ^ hy0 ^ hz0) & TMASK; idx[5] = (hx1 ^ hy0 ^ hz1) & TMASK;
  idx[6] = (hx1 ^ hy1 ^ hz0) & TMASK; idx[7] = (hx1 ^ hy1 ^ hz1) & TMASK;
}

// ---------------- split path: encode kernel ----------------
// 1 thread per point. No LDS, no MFMA -> low VGPR (launch_bounds min 6 waves/EU
// caps at ~85 VGPR) -> ~24 waves/CU of gather TLP. Features packed into 5
// bf16x8 regs (d-major j = d*10+l, same order as R2/R3-proven path) and stored
// block-chunked SoA: ws[FEAT_OFF + blk*20480 + c*4096 + tid*16], so every
// store instruction is 64 lanes x 16 B contiguous.
__global__ __launch_bounds__(256, 6)
void ngp_encode(const float* __restrict__ x, const float* __restrict__ cr,
                char* __restrict__ ws8, int N, KParams kp) {
  const int tid = threadIdx.x;
  const int n = blockIdx.x * 256 + tid;
  const int ncl = (n < N) ? n : 0;

  const float px = x[ncl * 3 + 0];
  const float py = x[ncl * 3 + 1];
  const float pz = x[ncl * 3 + 2];
  const float crv = cr[ncl];
  const float* dq = (const float*)(ws8 + DQ_OFF);
  const uint32* tb8 = (const uint32*)(ws8 + TAB_OFF_B);

  bf16x8 f[5];
#pragma unroll
  for (int l = 0; l < LVLS; ++l) {
    uint32 idx[8];
    float fx, fy, fz;
    level_idx(px, py, pz, kp.resf[l], idx, fx, fy, fz);
    const uint32* base = tb8 + l * TSIZE;
    uint32 q[8];
#pragma unroll
    for (int c = 0; c < 8; ++c) q[c] = base[idx[c]];
    float wx1 = fx, wx0 = 1.f - fx, wy1 = fy, wy0 = 1.f - fy, wz1 = fz, wz0 = 1.f - fz;
    float wxy00 = wx0 * wy0, wxy01 = wx0 * wy1, wxy10 = wx1 * wy0, wxy11 = wx1 * wy1;
    float w[8] = {wxy00 * wz0, wxy00 * wz1, wxy01 * wz0, wxy01 * wz1,
                  wxy10 * wz0, wxy10 * wz1, wxy11 * wz0, wxy11 * wz1};
    float a0 = 0.f, a1 = 0.f, a2 = 0.f, a3 = 0.f;
#pragma unroll
    for (int c = 0; c < 8; ++c) {
      a0 = fmaf(w[c], ub0(q[c]), a0);
      a1 = fmaf(w[c], ub1(q[c]), a1);
      a2 = fmaf(w[c], ub2(q[c]), a2);
      a3 = fmaf(w[c], ub3(q[c]), a3);
    }
    float s = erf_fast(rsqrtf(fmaxf(4.0f * (float)l * crv, 1e-12f))) * dq[l];
    float off = -128.f * s;
    // d-major feature index j = d*10 + l (identical to proven feat[] order)
    f[(l) >> 3][(l) & 7]           = (bf16)fmaf(a0, s, off);
    f[(10 + l) >> 3][(10 + l) & 7] = (bf16)fmaf(a1, s, off);
    f[(20 + l) >> 3][(20 + l) & 7] = (bf16)fmaf(a2, s, off);
    f[(30 + l) >> 3][(30 + l) & 7] = (bf16)fmaf(a3, s, off);
  }

  char* fb = ws8 + FEAT_OFF + (size_t)blockIdx.x * FEAT_BLK_BYTES;
#pragma unroll
  for (int c = 0; c < 5; ++c)
    *(bf16x8*)(fb + c * 4096 + tid * 16) = f[c];
}

// ---------------- shared MLP building block ----------------
__device__ __forceinline__ void gemm_stage(const bf16* __restrict__ Arow,
                                           const bf16* __restrict__ Bbase,
                                           const float* __restrict__ bvec,
                                           bf16* __restrict__ Hwr, int lr) {
  float bias[4];
#pragma unroll
  for (int nt = 0; nt < 4; ++nt) bias[nt] = bvec[nt * 16 + lr];
  f32x4 acc[4][4];
#pragma unroll
  for (int ms = 0; ms < 4; ++ms)
#pragma unroll
    for (int nt = 0; nt < 4; ++nt) {
      f32x4 a = {bias[nt], bias[nt], bias[nt], bias[nt]};
      acc[ms][nt] = a;
    }
  bf16x8 Bf[2][4];
#pragma unroll
  for (int ks = 0; ks < 2; ++ks)
#pragma unroll
    for (int nt = 0; nt < 4; ++nt)
      Bf[ks][nt] = *(const bf16x8*)(Bbase + nt * 1024 + ks * 32);
#pragma unroll
  for (int ks = 0; ks < 2; ++ks) {
    bf16x8 Af[4];
#pragma unroll
    for (int ms = 0; ms < 4; ++ms) Af[ms] = *(const bf16x8*)(Arow + ms * 1152 + ks * 32);
#pragma unroll
    for (int ms = 0; ms < 4; ++ms)
#pragma unroll
      for (int nt = 0; nt < 4; ++nt)
        acc[ms][nt] = __builtin_amdgcn_mfma_f32_16x16x32_bf16(Af[ms], Bf[ks][nt], acc[ms][nt], 0, 0, 0);
  }
#pragma unroll
  for (int ms = 0; ms < 4; ++ms)
#pragma unroll
    for (int nt = 0; nt < 4; ++nt)
#pragma unroll
      for (int r = 0; r < 4; ++r)
        Hwr[(ms * 16 + r) * 72 + nt * 16 + lr] = (bf16)selu_f(acc[ms][nt][r]);
}

// ---------------- split path: MLP kernel ----------------
// 256 threads (4 waves), 256 points per block. Stage rows from the feature
// buffer (coalesced 16B/lane), then the R6-proven 3-stage MFMA MLP.
__global__ __launch_bounds__(256)
void ngp_mlp(const char* __restrict__ ws8, const float* __restrict__ b1,
             const float* __restrict__ b2, const float* __restrict__ b3,
             float* __restrict__ out, int N) {
  __shared__ __align__(16) bf16 Hbuf[256 * 72];
  const int tid = threadIdx.x;

  {
    const char* fb = ws8 + FEAT_OFF + (size_t)blockIdx.x * FEAT_BLK_BYTES;
    bf16* row = Hbuf + tid * 72;
#pragma unroll
    for (int c = 0; c < 5; ++c)
      *(bf16x8*)(row + c * 8) = *(const bf16x8*)(fb + c * 4096 + tid * 16);
    bf16x8 z;
#pragma unroll
    for (int j = 0; j < 8; ++j) z[j] = (bf16)0.f;
    *(bf16x8*)(row + 40) = z;
    *(bf16x8*)(row + 48) = z;
    *(bf16x8*)(row + 56) = z;
  }
  __syncthreads();

  const int w = tid >> 6;
  const int lane = tid & 63;
  const int lr = lane & 15;
  const int quad = lane >> 4;
  const bf16* wsb = (const bf16*)ws8;

  const bf16* Arow = Hbuf + (w * 64 + lr) * 72 + quad * 8;
  bf16* Hwr = Hbuf + (w * 64 + quad * 4) * 72;

  gemm_stage(Arow, wsb + WOFF_W1 + lr * 64 + quad * 8, b1, Hwr, lr);
  __syncthreads();
  gemm_stage(Arow, wsb + WOFF_W2 + lr * 64 + quad * 8, b2, Hwr, lr);
  __syncthreads();

  f32x4 acc3[4];
  {
    float b3v = (lr < 13) ? b3[lr] : 0.f;
#pragma unroll
    for (int ms = 0; ms < 4; ++ms) {
      f32x4 a = {b3v, b3v, b3v, b3v};
      acc3[ms] = a;
    }
    const bf16* B3b = wsb + WOFF_W3 + lr * 64 + quad * 8;
    bf16x8 B3[2];
    B3[0] = *(const bf16x8*)(B3b);
    B3[1] = *(const bf16x8*)(B3b + 32);
#pragma unroll
    for (int ks = 0; ks < 2; ++ks) {
      bf16x8 Af[4];
#pragma unroll
      for (int ms = 0; ms < 4; ++ms) Af[ms] = *(const bf16x8*)(Arow + ms * 1152 + ks * 32);
#pragma unroll
      for (int ms = 0; ms < 4; ++ms)
        acc3[ms] = __builtin_amdgcn_mfma_f32_16x16x32_bf16(Af[ms], B3[ks], acc3[ms], 0, 0, 0);
    }
  }
  __syncthreads();
  float* ob = (float*)Hbuf;
  if (lr < 13) {
#pragma unroll
    for (int ms = 0; ms < 4; ++ms)
#pragma unroll
      for (int r = 0; r < 4; ++r)
        ob[(w * 64 + quad * 4 + ms * 16 + r) * 13 + lr] = acc3[ms][r];
  }
  __syncthreads();
  const int base = blockIdx.x * (256 * 13);
  if ((blockIdx.x + 1) * 256 <= N) {
    const float4* obv = (const float4*)ob;
    float4* og = (float4*)(out + base);
#pragma unroll
    for (int i = tid; i < 832; i += 256) og[i] = obv[i];
  } else {
    const int lim = N * 13 - base;
    for (int i = tid; i < 256 * 13; i += 256)
      if (i < lim) out[base + i] = ob[i];
  }
}

// ---------------- fallback: R6 fused kernel (proven) ----------------
template <bool TB>
__global__ __launch_bounds__(256)
void ngp_fused(const float* __restrict__ x, const float* __restrict__ cr,
               const float* __restrict__ tables, const char* __restrict__ ws8,
               const float* __restrict__ b1, const float* __restrict__ b2,
               const float* __restrict__ b3, float* __restrict__ out,
               int N, KParams kp) {
  __shared__ __align__(16) bf16 Hbuf[256 * 72];
  const int tid = threadIdx.x;
  const int n = blockIdx.x * 256 + tid;
  const int ncl = (n < N) ? n : 0;

  const float px = x[ncl * 3 + 0];
  const float py = x[ncl * 3 + 1];
  const float pz = x[ncl * 3 + 2];
  const float crv = cr[ncl];
  const float* dq = (const float*)(ws8 + DQ_OFF);

  float feat[40];
#pragma unroll 1
  for (int l = 0; l < LVLS; ++l) {
    uint32 idx[8];
    float fx, fy, fz;
    level_idx(px, py, pz, kp.resf[l], idx, fx, fy, fz);
    float fv[8][4];
    if (TB) {
      const uint32* base = ((const uint32*)(ws8 + TAB_OFF_B)) + l * TSIZE;
#pragma unroll
      for (int c = 0; c < 8; ++c) {
        uint32 q = base[idx[c]];
        fv[c][0] = ub0(q); fv[c][1] = ub1(q); fv[c][2] = ub2(q); fv[c][3] = ub3(q);
      }
    } else {
      const float4* tb = ((const float4*)tables) + l * TSIZE;
#pragma unroll
      for (int c = 0; c < 8; ++c) {
        float4 q = tb[idx[c]];
        fv[c][0] = q.x; fv[c][1] = q.y; fv[c][2] = q.z; fv[c][3] = q.w;
      }
    }
    float wx1 = fx, wx0 = 1.f - fx, wy1 = fy, wy0 = 1.f - fy, wz1 = fz, wz0 = 1.f - fz;
    float wxy00 = wx0 * wy0, wxy01 = wx0 * wy1, wxy10 = wx1 * wy0, wxy11 = wx1 * wy1;
    float w[8] = {wxy00 * wz0, wxy00 * wz1, wxy01 * wz0, wxy01 * wz1,
                  wxy10 * wz0, wxy10 * wz1, wxy11 * wz0, wxy11 * wz1};
    float a0 = 0.f, a1 = 0.f, a2 = 0.f, a3 = 0.f;
#pragma unroll
    for (int c = 0; c < 8; ++c) {
      a0 = fmaf(w[c], fv[c][0], a0);
      a1 = fmaf(w[c], fv[c][1], a1);
      a2 = fmaf(w[c], fv[c][2], a2);
      a3 = fmaf(w[c], fv[c][3], a3);
    }
    float s = erf_fast(rsqrtf(fmaxf(4.0f * (float)l * crv, 1e-12f)));
    if (TB) {
      s *= dq[l];
      float off = -128.f * s;
      feat[0 * 10 + l] = fmaf(a0, s, off);
      feat[1 * 10 + l] = fmaf(a1, s, off);
      feat[2 * 10 + l] = fmaf(a2, s, off);
      feat[3 * 10 + l] = fmaf(a3, s, off);
    } else {
      feat[0 * 10 + l] = a0 * s;
      feat[1 * 10 + l] = a1 * s;
      feat[2 * 10 + l] = a2 * s;
      feat[3 * 10 + l] = a3 * s;
    }
  }

  {
    bf16* row = Hbuf + tid * 72;
#pragma unroll
    for (int c = 0; c < 5; ++c) {
      bf16x8 v;
#pragma unroll
      for (int j = 0; j < 8; ++j) v[j] = (bf16)feat[c * 8 + j];
      *(bf16x8*)(row + c * 8) = v;
    }
    bf16x8 z;
#pragma unroll
    for (int j = 0; j < 8; ++j) z[j] = (bf16)0.f;
    *(bf16x8*)(row + 40) = z;
    *(bf16x8*)(row + 48) = z;
    *(bf16x8*)(row + 56) = z;
  }
  __syncthreads();

  const int w = tid >> 6;
  const int lane = tid & 63;
  const int lr = lane & 15;
  const int quad = lane >> 4;
  const bf16* wsb = (const bf16*)ws8;

  const bf16* Arow = Hbuf + (w * 64 + lr) * 72 + quad * 8;
  bf16* Hwr = Hbuf + (w * 64 + quad * 4) * 72;

  gemm_stage(Arow, wsb + WOFF_W1 + lr * 64 + quad * 8, b1, Hwr, lr);
  __syncthreads();
  gemm_stage(Arow, wsb + WOFF_W2 + lr * 64 + quad * 8, b2, Hwr, lr);
  __syncthreads();

  f32x4 acc3[4];
  {
    float b3v = (lr < 13) ? b3[lr] : 0.f;
#pragma unroll
    for (int ms = 0; ms < 4; ++ms) {
      f32x4 a = {b3v, b3v, b3v, b3v};
      acc3[ms] = a;
    }
    const bf16* B3b = wsb + WOFF_W3 + lr * 64 + quad * 8;
    bf16x8 B3[2];
    B3[0] = *(const bf16x8*)(B3b);
    B3[1] = *(const bf16x8*)(B3b + 32);
#pragma unroll
    for (int ks = 0; ks < 2; ++ks) {
      bf16x8 Af[4];
#pragma unroll
      for (int ms = 0; ms < 4; ++ms) Af[ms] = *(const bf16x8*)(Arow + ms * 1152 + ks * 32);
#pragma unroll
      for (int ms = 0; ms < 4; ++ms)
        acc3[ms] = __builtin_amdgcn_mfma_f32_16x16x32_bf16(Af[ms], B3[ks], acc3[ms], 0, 0, 0);
    }
  }
  __syncthreads();
  float* ob = (float*)Hbuf;
  if (lr < 13) {
#pragma unroll
    for (int ms = 0; ms < 4; ++ms)
#pragma unroll
      for (int r = 0; r < 4; ++r)
        ob[(w * 64 + quad * 4 + ms * 16 + r) * 13 + lr] = acc3[ms][r];
  }
  __syncthreads();
  const int base = blockIdx.x * (256 * 13);
  if ((blockIdx.x + 1) * 256 <= N) {
    const float4* obv = (const float4*)ob;
    float4* og = (float4*)(out + base);
#pragma unroll
    for (int i = tid; i < 832; i += 256) og[i] = obv[i];
  } else {
    const int lim = N * 13 - base;
    for (int i = tid; i < 256 * 13; i += 256)
      if (i < lim) out[base + i] = ob[i];
  }
}

// ---------------- host ----------------
extern "C" void kernel_launch(void* const* d_in, const int* in_sizes, int n_in,
                              void* d_out, int out_size, void* d_ws, size_t ws_size,
                              hipStream_t stream) {
  const float* x      = (const float*)d_in[0];
  const float* cr     = (const float*)d_in[1];
  const float* tables = (const float*)d_in[2];
  const float* W1     = (const float*)d_in[3];
  const float* b1     = (const float*)d_in[4];
  const float* W2     = (const float*)d_in[5];
  const float* b2     = (const float*)d_in[6];
  const float* W3     = (const float*)d_in[7];
  const float* b3     = (const float*)d_in[8];
  float* out = (float*)d_out;
  const int N = in_sizes[1];

  // RES with the exact double arithmetic Python uses (bit-identical hashing).
  KParams kp;
  double B = exp((log(16.0 * pow(2.0, 10.0)) - log(16.0)) / 9.0);
  for (int l = 0; l < LVLS; ++l) kp.resf[l] = (float)floor(16.0 * pow(B, (double)l));

  char* ws8 = (char*)d_ws;
  const int nblk = (N + 255) / 256;
  const bool tb = ws_size >= WS_TAB_NEEDED;
  const bool split = ws_size >= (size_t)FEAT_OFF + (size_t)nblk * FEAT_BLK_BYTES;

  const int qblocks = (TAB_ELEMS_F / 4 + 255) / 256;
  if (tb) {
    (void)hipMemsetAsync(ws8 + SC_OFF, 0, 64, stream);
    scale_kernel<<<qblocks, 256, 0, stream>>>(tables, (unsigned*)(ws8 + SC_OFF));
    quant_kernel<<<qblocks, 256, 0, stream>>>(W1, W2, W3, tables, ws8, 1);
  } else {
    quant_kernel<<<(W_ELEMS + 255) / 256, 256, 0, stream>>>(W1, W2, W3, tables, ws8, 0);
  }

  if (split) {
    ngp_encode<<<nblk, 256, 0, stream>>>(x, cr, ws8, N, kp);
    ngp_mlp<<<nblk, 256, 0, stream>>>(ws8, b1, b2, b3, out, N);
  } else if (tb) {
    ngp_fused<true><<<nblk, 256, 0, stream>>>(x, cr, tables, ws8, b1, b2, b3, out, N, kp);
  } else {
    ngp_fused<false><<<nblk, 256, 0, stream>>>(x, cr, tables, ws8, b1, b2, b3, out, N, kp);
  }
}